// Round 1
// baseline (755.477 us; speedup 1.0000x reference)
//
#include <hip/hip_runtime.h>
#include <math.h>

// GCN 2-layer: h = softmax( L2( relu( L1(x) ) ) ), L(x) = Dins^-1/2 A Douts^-1/2 x W + b
// N=100000 nodes, E=1.6M edges, feats 128 -> 64 -> 16, all fp32.

constexpr int N_NODES = 100000;
constexpr int N_EDGES = 1600000;
constexpr int IN_F    = 128;
constexpr int HID     = 64;
constexpr int NC      = 16;

// ---------------- degree histogram ----------------
__global__ void k_deg(const int* __restrict__ src, const int* __restrict__ dst,
                      float* __restrict__ deg_out, float* __restrict__ deg_in) {
    int i = blockIdx.x * blockDim.x + threadIdx.x;
    if (i < N_EDGES) {
        atomicAdd(&deg_out[src[i]], 1.0f);
        atomicAdd(&deg_in[dst[i]], 1.0f);
    }
}

// ---------------- rsqrt(clip(deg,1)) in place ----------------
__global__ void k_norm(float* __restrict__ ns, float* __restrict__ nd) {
    int i = blockIdx.x * blockDim.x + threadIdx.x;
    if (i < N_NODES) {
        ns[i] = 1.0f / sqrtf(fmaxf(ns[i], 1.0f));
        nd[i] = 1.0f / sqrtf(fmaxf(nd[i], 1.0f));
    }
}

// ---------------- GEMM1: h1[i][j] = ns[i] * sum_k x[i][k] W1[k][j] ----------------
// 16 rows per block-iter; thread t: jq = t&15 (4 outputs), rl = t>>4 (row).
// W1 (128x64 = 32KB) cached in LDS; x tile padded to stride 132 (2-way banks = free).
__global__ __launch_bounds__(256) void k_gemm1(
        const float* __restrict__ x, const float* __restrict__ W1,
        const float* __restrict__ norm_src, float* __restrict__ h1) {
    __shared__ float Ws[IN_F * HID];        // 32 KB
    __shared__ float xs[16 * 132];          // 8.25 KB, stride 132: bank = (rl*4+k)%32 -> 2-way (free)
    const int t = threadIdx.x;
    for (int i = t * 4; i < IN_F * HID; i += 256 * 4)
        *(float4*)&Ws[i] = *(const float4*)&W1[i];
    const int jq = t & 15;
    const int rl = t >> 4;
    for (int row0 = blockIdx.x * 16; row0 < N_NODES; row0 += gridDim.x * 16) {
        __syncthreads();   // xs reuse from previous iter (also orders Ws load on iter 0)
        for (int i = t; i < 16 * (IN_F / 4); i += 256) {
            int rr = i >> 5, cc = i & 31;
            int gr = row0 + rr;
            float4 v = (gr < N_NODES) ? *(const float4*)&x[(size_t)gr * IN_F + cc * 4]
                                      : float4{0.f, 0.f, 0.f, 0.f};
            *(float4*)&xs[rr * 132 + cc * 4] = v;
        }
        __syncthreads();
        int r = row0 + rl;
        if (r < N_NODES) {
            float4 acc = {0.f, 0.f, 0.f, 0.f};
            #pragma unroll
            for (int k = 0; k < IN_F; k += 4) {
                float4 xv = *(float4*)&xs[rl * 132 + k];
                float4 w0 = *(float4*)&Ws[(k + 0) * HID + jq * 4];
                float4 w1 = *(float4*)&Ws[(k + 1) * HID + jq * 4];
                float4 w2 = *(float4*)&Ws[(k + 2) * HID + jq * 4];
                float4 w3 = *(float4*)&Ws[(k + 3) * HID + jq * 4];
                acc.x += xv.x * w0.x + xv.y * w1.x + xv.z * w2.x + xv.w * w3.x;
                acc.y += xv.x * w0.y + xv.y * w1.y + xv.z * w2.y + xv.w * w3.y;
                acc.z += xv.x * w0.z + xv.y * w1.z + xv.z * w2.z + xv.w * w3.z;
                acc.w += xv.x * w0.w + xv.y * w1.w + xv.z * w2.w + xv.w * w3.w;
            }
            float ns = norm_src[r];
            acc.x *= ns; acc.y *= ns; acc.z *= ns; acc.w *= ns;
            *(float4*)&h1[(size_t)r * HID + jq * 4] = acc;
        }
    }
}

// ---------------- scatter1: agg1[dst[e]] += h1[src[e]] (64 feats) ----------------
// one wave == one edge (64 lanes = 64 feats); index loads are wave-uniform broadcast.
__global__ void k_scatter1(const int* __restrict__ src, const int* __restrict__ dst,
                           const float* __restrict__ h1, float* __restrict__ agg1) {
    int gid = blockIdx.x * blockDim.x + threadIdx.x;
    int e = gid >> 6, j = gid & 63;
    if (e < N_EDGES) {
        int s = src[e], d = dst[e];
        atomicAdd(&agg1[(size_t)d * HID + j], h1[(size_t)s * HID + j]);
    }
}

// ---------------- epilogue1: agg1 = relu(agg1*nd + b1) in place ----------------
__global__ void k_post1(float* __restrict__ agg1, const float* __restrict__ nd,
                        const float* __restrict__ b1) {
    int gid = blockIdx.x * blockDim.x + threadIdx.x;
    int i = gid >> 4, q = gid & 15;
    if (i < N_NODES) {
        float4 v = *(float4*)&agg1[(size_t)i * HID + q * 4];
        float4 bb = *(const float4*)&b1[q * 4];
        float n = nd[i];
        v.x = fmaxf(v.x * n + bb.x, 0.f);
        v.y = fmaxf(v.y * n + bb.y, 0.f);
        v.z = fmaxf(v.z * n + bb.z, 0.f);
        v.w = fmaxf(v.w * n + bb.w, 0.f);
        *(float4*)&agg1[(size_t)i * HID + q * 4] = v;
    }
}

// ---------------- GEMM2: h2[i][j] = ns[i] * sum_k hin[i][k] W2[k][j] ----------------
// 64 rows per block-iter; thread t: jq = t&3 (4 of 16 outputs), rl = t>>2.
__global__ __launch_bounds__(256) void k_gemm2(
        const float* __restrict__ hin, const float* __restrict__ W2,
        const float* __restrict__ norm_src, float* __restrict__ h2) {
    __shared__ float Ws[HID * NC];          // 4 KB
    __shared__ float xs[64 * 68];           // 17 KB, stride 68: bank = (rl*4+k)%32 -> 2-way (free)
    const int t = threadIdx.x;
    for (int i = t * 4; i < HID * NC; i += 256 * 4)
        *(float4*)&Ws[i] = *(const float4*)&W2[i];
    const int jq = t & 3;
    const int rl = t >> 2;
    for (int row0 = blockIdx.x * 64; row0 < N_NODES; row0 += gridDim.x * 64) {
        __syncthreads();
        for (int i = t; i < 64 * (HID / 4); i += 256) {
            int rr = i >> 4, cc = i & 15;
            int gr = row0 + rr;
            float4 v = (gr < N_NODES) ? *(const float4*)&hin[(size_t)gr * HID + cc * 4]
                                      : float4{0.f, 0.f, 0.f, 0.f};
            *(float4*)&xs[rr * 68 + cc * 4] = v;
        }
        __syncthreads();
        int r = row0 + rl;
        if (r < N_NODES) {
            float4 acc = {0.f, 0.f, 0.f, 0.f};
            #pragma unroll
            for (int k = 0; k < HID; k += 4) {
                float4 xv = *(float4*)&xs[rl * 68 + k];
                float4 w0 = *(float4*)&Ws[(k + 0) * NC + jq * 4];
                float4 w1 = *(float4*)&Ws[(k + 1) * NC + jq * 4];
                float4 w2 = *(float4*)&Ws[(k + 2) * NC + jq * 4];
                float4 w3 = *(float4*)&Ws[(k + 3) * NC + jq * 4];
                acc.x += xv.x * w0.x + xv.y * w1.x + xv.z * w2.x + xv.w * w3.x;
                acc.y += xv.x * w0.y + xv.y * w1.y + xv.z * w2.y + xv.w * w3.y;
                acc.z += xv.x * w0.z + xv.y * w1.z + xv.z * w2.z + xv.w * w3.z;
                acc.w += xv.x * w0.w + xv.y * w1.w + xv.z * w2.w + xv.w * w3.w;
            }
            float ns = norm_src[r];
            acc.x *= ns; acc.y *= ns; acc.z *= ns; acc.w *= ns;
            *(float4*)&h2[(size_t)r * NC + jq * 4] = acc;
        }
    }
}

// ---------------- scatter2: agg2[dst[e]] += h2[src[e]] (16 feats) ----------------
__global__ void k_scatter2(const int* __restrict__ src, const int* __restrict__ dst,
                           const float* __restrict__ h2, float* __restrict__ agg2) {
    int gid = blockIdx.x * blockDim.x + threadIdx.x;
    int e = gid >> 4, j = gid & 15;
    if (e < N_EDGES) {
        int s = src[e], d = dst[e];
        atomicAdd(&agg2[(size_t)d * NC + j], h2[(size_t)s * NC + j]);
    }
}

// ---------------- softmax(agg2*nd + b2) ----------------
__global__ void k_softmax(const float* __restrict__ agg2, const float* __restrict__ nd,
                          const float* __restrict__ b2, float* __restrict__ out) {
    int i = blockIdx.x * blockDim.x + threadIdx.x;
    if (i >= N_NODES) return;
    float n = nd[i];
    float v[NC];
    #pragma unroll
    for (int q = 0; q < 4; ++q) {
        float4 a = *(const float4*)&agg2[(size_t)i * NC + q * 4];
        float4 bb = *(const float4*)&b2[q * 4];
        v[q * 4 + 0] = a.x * n + bb.x;
        v[q * 4 + 1] = a.y * n + bb.y;
        v[q * 4 + 2] = a.z * n + bb.z;
        v[q * 4 + 3] = a.w * n + bb.w;
    }
    float m = v[0];
    #pragma unroll
    for (int j = 1; j < NC; ++j) m = fmaxf(m, v[j]);
    float s = 0.f;
    #pragma unroll
    for (int j = 0; j < NC; ++j) { v[j] = __expf(v[j] - m); s += v[j]; }
    float inv = 1.0f / s;
    #pragma unroll
    for (int q = 0; q < 4; ++q) {
        float4 o = { v[q*4+0] * inv, v[q*4+1] * inv, v[q*4+2] * inv, v[q*4+3] * inv };
        *(float4*)&out[(size_t)i * NC + q * 4] = o;
    }
}

extern "C" void kernel_launch(void* const* d_in, const int* in_sizes, int n_in,
                              void* d_out, int out_size, void* d_ws, size_t ws_size,
                              hipStream_t stream) {
    const float* x   = (const float*)d_in[0];
    const int*   src = (const int*)  d_in[1];
    const int*   dst = (const int*)  d_in[2];
    const float* W1  = (const float*)d_in[3];
    const float* b1  = (const float*)d_in[4];
    const float* W2  = (const float*)d_in[5];
    const float* b2  = (const float*)d_in[6];
    float* out = (float*)d_out;

    // ws layout (floats): norms 2N | agg1 64N | h1 64N. agg2(16N)+h2(16N) alias
    // dead h1 after scatter1. Peak = 130N floats = 52 MB.
    float* ws       = (float*)d_ws;
    const size_t N  = N_NODES;
    float* norm_src = ws;            // [0, N)
    float* norm_dst = ws + N;        // [N, 2N)
    float* agg1     = ws + 2 * N;    // [2N, 66N)
    float* h1       = ws + 66 * N;   // [66N, 130N)
    float* agg2     = ws + 66 * N;   // aliases h1 (dead after scatter1)
    float* h2       = ws + 82 * N;   // aliases h1 tail

    // zero norms + agg1
    hipMemsetAsync(d_ws, 0, (size_t)66 * N * sizeof(float), stream);

    k_deg<<<(N_EDGES + 255) / 256, 256, 0, stream>>>(src, dst, norm_src, norm_dst);
    k_norm<<<(N_NODES + 255) / 256, 256, 0, stream>>>(norm_src, norm_dst);
    k_gemm1<<<2048, 256, 0, stream>>>(x, W1, norm_src, h1);
    k_scatter1<<<(N_EDGES * 64) / 256, 256, 0, stream>>>(src, dst, h1, agg1);
    k_post1<<<(N_NODES * 16 + 255) / 256, 256, 0, stream>>>(agg1, norm_dst, b1);
    k_gemm2<<<2048, 256, 0, stream>>>(agg1, W2, norm_src, h2);
    // zero agg2 (aliases h1 — h1 is dead now)
    hipMemsetAsync((void*)agg2, 0, (size_t)16 * N * sizeof(float), stream);
    k_scatter2<<<(N_EDGES * 16) / 256, 256, 0, stream>>>(src, dst, h2, agg2);
    k_softmax<<<(N_NODES + 255) / 256, 256, 0, stream>>>(agg2, norm_dst, b2, out);
}

// Round 2
// 535.295 us; speedup vs baseline: 1.4113x; 1.4113x over previous
//
#include <hip/hip_runtime.h>
#include <math.h>

// GCN 2-layer, fp32. Round 2: replace float-atomic scatter with CSR-by-dst
// gather aggregation (deterministic sums, writes each output row once).

constexpr int N_NODES = 100000;
constexpr int N_EDGES = 1600000;
constexpr int IN_F    = 128;
constexpr int HID     = 64;
constexpr int NC      = 16;

// ---------------- degree histogram (int atomics) ----------------
__global__ void k_deg(const int* __restrict__ src, const int* __restrict__ dst,
                      int* __restrict__ deg_out, int* __restrict__ deg_in) {
    int i = blockIdx.x * blockDim.x + threadIdx.x;
    if (i < N_EDGES) {
        atomicAdd(&deg_out[src[i]], 1);
        atomicAdd(&deg_in[dst[i]], 1);
    }
}

// ---------------- norms from int degrees ----------------
__global__ void k_norm(const int* __restrict__ dego, const int* __restrict__ degi,
                       float* __restrict__ ns, float* __restrict__ nd) {
    int i = blockIdx.x * blockDim.x + threadIdx.x;
    if (i < N_NODES) {
        ns[i] = 1.0f / sqrtf(fmaxf((float)dego[i], 1.0f));
        nd[i] = 1.0f / sqrtf(fmaxf((float)degi[i], 1.0f));
    }
}

// ---------------- exclusive scan of deg_in -> row_start (3 kernels) ----------------
// scan1: per-block (256 elems) totals
__global__ void k_scan1(const int* __restrict__ degi, int* __restrict__ blk) {
    int t = threadIdx.x, b = blockIdx.x;
    int i = b * 256 + t;
    int x = (i < N_NODES) ? degi[i] : 0;
    int lane = t & 63, wid = t >> 6;
    int v = x;
    #pragma unroll
    for (int d = 1; d < 64; d <<= 1) { int u = __shfl_up(v, d, 64); if (lane >= d) v += u; }
    __shared__ int wsum[4];
    if (lane == 63) wsum[wid] = v;
    __syncthreads();
    if (t == 0) blk[b] = wsum[0] + wsum[1] + wsum[2] + wsum[3];
}
// scan2: scan the 392 block sums in one block (in place -> exclusive offsets)
__global__ void k_scan2(int* __restrict__ blk, int nblk) {
    int t = threadIdx.x;                     // 512 threads
    int x = (t < nblk) ? blk[t] : 0;
    int lane = t & 63, wid = t >> 6;
    int v = x;
    #pragma unroll
    for (int d = 1; d < 64; d <<= 1) { int u = __shfl_up(v, d, 64); if (lane >= d) v += u; }
    __shared__ int wsum[8];
    if (lane == 63) wsum[wid] = v;
    __syncthreads();
    int woff = 0;
    for (int w = 0; w < wid; ++w) woff += wsum[w];
    if (t < nblk) blk[t] = woff + v - x;     // exclusive
}
// scan3: recompute local scan, add block offset -> row_start + cursor copy
__global__ void k_scan3(const int* __restrict__ degi, const int* __restrict__ blk,
                        int* __restrict__ row_start, int* __restrict__ cursor) {
    int t = threadIdx.x, b = blockIdx.x;
    int i = b * 256 + t;
    int x = (i < N_NODES) ? degi[i] : 0;
    int lane = t & 63, wid = t >> 6;
    int v = x;
    #pragma unroll
    for (int d = 1; d < 64; d <<= 1) { int u = __shfl_up(v, d, 64); if (lane >= d) v += u; }
    __shared__ int wsum[4];
    if (lane == 63) wsum[wid] = v;
    __syncthreads();
    int woff = 0;
    for (int w = 0; w < wid; ++w) woff += wsum[w];
    if (i < N_NODES) {
        int rs = blk[b] + woff + v - x;      // exclusive
        row_start[i] = rs;
        cursor[i]    = rs;
    }
}

// ---------------- CSR fill: csr_src sorted by dst ----------------
__global__ void k_fill(const int* __restrict__ src, const int* __restrict__ dst,
                       int* __restrict__ cursor, int* __restrict__ csr_src) {
    int e = blockIdx.x * blockDim.x + threadIdx.x;
    if (e < N_EDGES) {
        int pos = atomicAdd(&cursor[dst[e]], 1);
        csr_src[pos] = src[e];
    }
}

// ---------------- GEMM1: h1[i][j] = ns[i] * sum_k x[i][k] W1[k][j] ----------------
__global__ __launch_bounds__(256) void k_gemm1(
        const float* __restrict__ x, const float* __restrict__ W1,
        const float* __restrict__ norm_src, float* __restrict__ h1) {
    __shared__ float Ws[IN_F * HID];        // 32 KB
    __shared__ float xs[16 * 132];          // stride 132 -> 2-way banks (free)
    const int t = threadIdx.x;
    for (int i = t * 4; i < IN_F * HID; i += 256 * 4)
        *(float4*)&Ws[i] = *(const float4*)&W1[i];
    const int jq = t & 15;
    const int rl = t >> 4;
    for (int row0 = blockIdx.x * 16; row0 < N_NODES; row0 += gridDim.x * 16) {
        __syncthreads();
        for (int i = t; i < 16 * (IN_F / 4); i += 256) {
            int rr = i >> 5, cc = i & 31;
            int gr = row0 + rr;
            float4 v = (gr < N_NODES) ? *(const float4*)&x[(size_t)gr * IN_F + cc * 4]
                                      : float4{0.f, 0.f, 0.f, 0.f};
            *(float4*)&xs[rr * 132 + cc * 4] = v;
        }
        __syncthreads();
        int r = row0 + rl;
        if (r < N_NODES) {
            float4 acc = {0.f, 0.f, 0.f, 0.f};
            #pragma unroll
            for (int k = 0; k < IN_F; k += 4) {
                float4 xv = *(float4*)&xs[rl * 132 + k];
                float4 w0 = *(float4*)&Ws[(k + 0) * HID + jq * 4];
                float4 w1 = *(float4*)&Ws[(k + 1) * HID + jq * 4];
                float4 w2 = *(float4*)&Ws[(k + 2) * HID + jq * 4];
                float4 w3 = *(float4*)&Ws[(k + 3) * HID + jq * 4];
                acc.x += xv.x * w0.x + xv.y * w1.x + xv.z * w2.x + xv.w * w3.x;
                acc.y += xv.x * w0.y + xv.y * w1.y + xv.z * w2.y + xv.w * w3.y;
                acc.z += xv.x * w0.z + xv.y * w1.z + xv.z * w2.z + xv.w * w3.z;
                acc.w += xv.x * w0.w + xv.y * w1.w + xv.z * w2.w + xv.w * w3.w;
            }
            float ns = norm_src[r];
            acc.x *= ns; acc.y *= ns; acc.z *= ns; acc.w *= ns;
            *(float4*)&h1[(size_t)r * HID + jq * 4] = acc;
        }
    }
}

// ---------------- agg1: one wave per node, 64 lanes = 64 feats ----------------
// h1r[n][j] = relu( nd[n] * sum_{e in CSR row n} h1[csr_src[e]][j] + b1[j] )
__global__ __launch_bounds__(256) void k_agg1(
        const int* __restrict__ row_start, const int* __restrict__ degi,
        const int* __restrict__ csr_src, const float* __restrict__ h1,
        const float* __restrict__ nd, const float* __restrict__ b1,
        float* __restrict__ h1r) {
    int node = blockIdx.x * 4 + (threadIdx.x >> 6);
    int lane = threadIdx.x & 63;
    if (node >= N_NODES) return;
    int beg = row_start[node];
    int end = beg + degi[node];
    float acc = 0.f;
    int p = beg;
    for (; p + 1 < end; p += 2) {
        int s0 = csr_src[p], s1 = csr_src[p + 1];
        float a = h1[(size_t)s0 * HID + lane];
        float b = h1[(size_t)s1 * HID + lane];
        acc += a; acc += b;
    }
    if (p < end) acc += h1[(size_t)csr_src[p] * HID + lane];
    float v = acc * nd[node] + b1[lane];
    h1r[(size_t)node * HID + lane] = fmaxf(v, 0.f);
}

// ---------------- GEMM2: h2[i][j] = ns[i] * sum_k h1r[i][k] W2[k][j] ----------------
__global__ __launch_bounds__(256) void k_gemm2(
        const float* __restrict__ hin, const float* __restrict__ W2,
        const float* __restrict__ norm_src, float* __restrict__ h2) {
    __shared__ float Ws[HID * NC];          // 4 KB
    __shared__ float xs[64 * 68];           // stride 68 -> 2-way banks (free)
    const int t = threadIdx.x;
    for (int i = t * 4; i < HID * NC; i += 256 * 4)
        *(float4*)&Ws[i] = *(const float4*)&W2[i];
    const int jq = t & 3;
    const int rl = t >> 2;
    for (int row0 = blockIdx.x * 64; row0 < N_NODES; row0 += gridDim.x * 64) {
        __syncthreads();
        for (int i = t; i < 64 * (HID / 4); i += 256) {
            int rr = i >> 4, cc = i & 15;
            int gr = row0 + rr;
            float4 v = (gr < N_NODES) ? *(const float4*)&hin[(size_t)gr * HID + cc * 4]
                                      : float4{0.f, 0.f, 0.f, 0.f};
            *(float4*)&xs[rr * 68 + cc * 4] = v;
        }
        __syncthreads();
        int r = row0 + rl;
        if (r < N_NODES) {
            float4 acc = {0.f, 0.f, 0.f, 0.f};
            #pragma unroll
            for (int k = 0; k < HID; k += 4) {
                float4 xv = *(float4*)&xs[rl * 68 + k];
                float4 w0 = *(float4*)&Ws[(k + 0) * NC + jq * 4];
                float4 w1 = *(float4*)&Ws[(k + 1) * NC + jq * 4];
                float4 w2 = *(float4*)&Ws[(k + 2) * NC + jq * 4];
                float4 w3 = *(float4*)&Ws[(k + 3) * NC + jq * 4];
                acc.x += xv.x * w0.x + xv.y * w1.x + xv.z * w2.x + xv.w * w3.x;
                acc.y += xv.x * w0.y + xv.y * w1.y + xv.z * w2.y + xv.w * w3.y;
                acc.z += xv.x * w0.z + xv.y * w1.z + xv.z * w2.z + xv.w * w3.z;
                acc.w += xv.x * w0.w + xv.y * w1.w + xv.z * w2.w + xv.w * w3.w;
            }
            float ns = norm_src[r];
            acc.x *= ns; acc.y *= ns; acc.z *= ns; acc.w *= ns;
            *(float4*)&h2[(size_t)r * NC + jq * 4] = acc;
        }
    }
}

// ---------------- agg2 + softmax: 16 lanes per node ----------------
__global__ __launch_bounds__(256) void k_agg2(
        const int* __restrict__ row_start, const int* __restrict__ degi,
        const int* __restrict__ csr_src, const float* __restrict__ h2,
        const float* __restrict__ nd, const float* __restrict__ b2,
        float* __restrict__ out) {
    int t = threadIdx.x;
    int node = blockIdx.x * 16 + (t >> 4);
    int lane = t & 15;
    if (node >= N_NODES) return;
    int beg = row_start[node];
    int end = beg + degi[node];
    float acc = 0.f;
    int p = beg;
    for (; p + 1 < end; p += 2) {
        int s0 = csr_src[p], s1 = csr_src[p + 1];
        float a = h2[(size_t)s0 * NC + lane];
        float b = h2[(size_t)s1 * NC + lane];
        acc += a; acc += b;
    }
    if (p < end) acc += h2[(size_t)csr_src[p] * NC + lane];
    float val = acc * nd[node] + b2[lane];
    // softmax across the 16-lane group
    float m = val;
    #pragma unroll
    for (int d = 8; d >= 1; d >>= 1) m = fmaxf(m, __shfl_xor(m, d, 16));
    float e = __expf(val - m);
    float s = e;
    #pragma unroll
    for (int d = 8; d >= 1; d >>= 1) s += __shfl_xor(s, d, 16);
    out[(size_t)node * NC + lane] = e / s;
}

extern "C" void kernel_launch(void* const* d_in, const int* in_sizes, int n_in,
                              void* d_out, int out_size, void* d_ws, size_t ws_size,
                              hipStream_t stream) {
    const float* x   = (const float*)d_in[0];
    const int*   src = (const int*)  d_in[1];
    const int*   dst = (const int*)  d_in[2];
    const float* W1  = (const float*)d_in[3];
    const float* b1  = (const float*)d_in[4];
    const float* W2  = (const float*)d_in[5];
    const float* b2  = (const float*)d_in[6];
    float* out = (float*)d_out;

    // ws layout (4-byte words), N = 100000 (multiple of 4):
    //   [0,N)      norm_src        [N,2N)      norm_dst
    //   [2N,66N)   hbuf1: h1 (gemm1 out) then h2 (gemm2 out, 16N, aliased)
    //   [66N,130N) hbuf2: h1r (agg1 out)
    //   [130N,131N) deg_out -> cursor (reused)
    //   [131N,132N) deg_in (kept: row end = row_start + deg_in)
    //   [132N,133N) row_start
    //   [133N,133N+512) blk sums
    //   [133N+512, ...) csr_src (E ints)
    // total ~= 133N + 512 + E words ~= 59.6 MB
    const size_t N = N_NODES;
    float* ws       = (float*)d_ws;
    int*   wsI      = (int*)d_ws;
    float* norm_src = ws;
    float* norm_dst = ws + N;
    float* h1       = ws + 2 * N;          // hbuf1
    float* h2       = ws + 2 * N;          // alias (h1 dead after agg1)
    float* h1r      = ws + 66 * N;         // hbuf2
    int*   deg_out  = wsI + 130 * N;       // reused as cursor after k_norm
    int*   deg_in   = wsI + 131 * N;
    int*   row_st   = wsI + 132 * N;
    int*   blk      = wsI + 133 * N;
    int*   csr_src  = wsI + 133 * N + 512;
    int*   cursor   = deg_out;

    const int NBLK = (N_NODES + 255) / 256;   // 391 -> pad to scan block count
    const int SCAN_BLKS = (N_NODES + 255) / 256;  // 391 blocks of 256 elems

    // zero the two degree arrays only (0.8 MB)
    hipMemsetAsync((void*)deg_out, 0, 2 * N * sizeof(int), stream);

    k_deg<<<(N_EDGES + 255) / 256, 256, 0, stream>>>(src, dst, deg_out, deg_in);
    k_norm<<<NBLK, 256, 0, stream>>>(deg_out, deg_in, norm_src, norm_dst);
    k_scan1<<<SCAN_BLKS, 256, 0, stream>>>(deg_in, blk);
    k_scan2<<<1, 512, 0, stream>>>(blk, SCAN_BLKS);
    k_scan3<<<SCAN_BLKS, 256, 0, stream>>>(deg_in, blk, row_st, cursor);
    k_fill<<<(N_EDGES + 255) / 256, 256, 0, stream>>>(src, dst, cursor, csr_src);
    k_gemm1<<<2048, 256, 0, stream>>>(x, W1, norm_src, h1);
    k_agg1<<<(N_NODES + 3) / 4, 256, 0, stream>>>(row_st, deg_in, csr_src, h1,
                                                  norm_dst, b1, h1r);
    k_gemm2<<<2048, 256, 0, stream>>>(h1r, W2, norm_src, h2);
    k_agg2<<<(N_NODES + 15) / 16, 256, 0, stream>>>(row_st, deg_in, csr_src, h2,
                                                    norm_dst, b2, out);
}

// Round 3
// 376.496 us; speedup vs baseline: 2.0066x; 1.4218x over previous
//
#include <hip/hip_runtime.h>
#include <math.h>

// GCN 2-layer, fp32. Round 3: random-global-atomic-free CSR build via
// two-level multisplit (LDS histograms + coalesced streams). The ~25 G
// random-line-ops/s ceiling measured in rounds 1-2 is avoided entirely.

constexpr int N_NODES = 100000;
constexpr int N_EDGES = 1600000;
constexpr int IN_F    = 128;
constexpr int HID     = 64;
constexpr int NC      = 16;

constexpr int NBLK_P  = 128;                 // partition blocks
constexpr int EPB     = N_EDGES / NBLK_P;    // 12500 edges per partition block
constexpr int NB_D    = 391;                 // dst buckets (256 nodes each)
constexpr int NB_ALL  = 2 * NB_D;            // 782: [0,391) dst, [391,782) src

// ---------------- p1: per-block bucket histogram (both keys) ----------------
__global__ __launch_bounds__(256) void k_p1(const int* __restrict__ src,
                                            const int* __restrict__ dst,
                                            int* __restrict__ gHist) {
    __shared__ int hist[NB_ALL];
    const int t = threadIdx.x, b = blockIdx.x;
    for (int i = t; i < NB_ALL; i += 256) hist[i] = 0;
    __syncthreads();
    const int beg = b * EPB, end = beg + EPB;
    for (int i = beg + t; i < end; i += 256) {
        atomicAdd(&hist[dst[i] >> 8], 1);
        atomicAdd(&hist[NB_D + (src[i] >> 8)], 1);
    }
    __syncthreads();
    for (int i = t; i < NB_ALL; i += 256)
        gHist[b * NB_ALL + i] = hist[i];     // coalesced
}

// ---------------- p2: column scan -> cursors (in place) + bucket starts ------
__global__ __launch_bounds__(1024) void k_p2(int* __restrict__ gHist,
                                             int* __restrict__ bucketStart) {
    const int t = threadIdx.x;               // 1024 threads, 782 active columns
    int total = 0;
    if (t < NB_ALL) {
        for (int blk = 0; blk < NBLK_P; ++blk) {
            int idx = blk * NB_ALL + t;      // coalesced across threads
            int v = gHist[idx];
            gHist[idx] = total;              // local exclusive prefix
            total += v;
        }
    }
    // block exclusive scan of `total` over 782 columns
    int v = total;
    int lane = t & 63, wid = t >> 6;
    #pragma unroll
    for (int d = 1; d < 64; d <<= 1) { int u = __shfl_up(v, d, 64); if (lane >= d) v += u; }
    __shared__ int wsum[16];
    if (lane == 63) wsum[wid] = v;
    __syncthreads();
    int woff = 0;
    for (int w = 0; w < wid; ++w) woff += wsum[w];
    int colStart = woff + v - total;         // exclusive
    if (t < NB_ALL) {
        bucketStart[t] = colStart;
        if (t == NB_ALL - 1) bucketStart[NB_ALL] = colStart + total;  // = 2E
        for (int blk = 0; blk < NBLK_P; ++blk)
            gHist[blk * NB_ALL + t] += colStart;   // now global cursors
    }
}

// ---------------- p3: scatter edges into buckets (LDS cursors) ----------------
// dst-buckets: 4B entry (dstLocal<<17)|src ; src-buckets: 1B entry srcLocal.
__global__ __launch_bounds__(256) void k_p3(const int* __restrict__ src,
                                            const int* __restrict__ dst,
                                            const int* __restrict__ gCursor,
                                            unsigned int* __restrict__ ebufD,
                                            unsigned char* __restrict__ ebufS) {
    __shared__ int curs[NB_ALL];
    const int t = threadIdx.x, b = blockIdx.x;
    for (int i = t; i < NB_ALL; i += 256) curs[i] = gCursor[b * NB_ALL + i];
    __syncthreads();
    const int beg = b * EPB, end = beg + EPB;
    for (int i = beg + t; i < end; i += 256) {
        int d = dst[i], s = src[i];
        int pD = atomicAdd(&curs[d >> 8], 1);
        ebufD[pD] = ((unsigned)(d & 255) << 17) | (unsigned)s;
        int pS = atomicAdd(&curs[NB_D + (s >> 8)], 1);
        ebufS[pS - N_EDGES] = (unsigned char)(s & 255);
    }
}

// ---------------- bcsr: per-bucket CSR build + norm_dst + row_start ----------
__global__ __launch_bounds__(256) void k_bcsr(const int* __restrict__ bucketStart,
                                              const unsigned int* __restrict__ ebufD,
                                              int* __restrict__ row_start,
                                              float* __restrict__ norm_dst,
                                              int* __restrict__ csr_src) {
    __shared__ int cnt[256];
    __shared__ int curs[256];
    __shared__ int wsum[4];
    const int t = threadIdx.x, b = blockIdx.x;
    const int beg = bucketStart[b], end = bucketStart[b + 1];
    cnt[t] = 0;
    __syncthreads();
    for (int i = beg + t; i < end; i += 256)
        atomicAdd(&cnt[ebufD[i] >> 17], 1);
    __syncthreads();
    // exclusive block scan of cnt
    int x = cnt[t];
    int v = x;
    int lane = t & 63, wid = t >> 6;
    #pragma unroll
    for (int d = 1; d < 64; d <<= 1) { int u = __shfl_up(v, d, 64); if (lane >= d) v += u; }
    if (lane == 63) wsum[wid] = v;
    __syncthreads();
    int woff = 0;
    for (int w = 0; w < wid; ++w) woff += wsum[w];
    int rs = woff + v - x;                   // exclusive prefix
    int node = b * 256 + t;
    if (node <= N_NODES) row_start[node] = beg + rs;
    if (node <  N_NODES) norm_dst[node] = 1.0f / sqrtf(fmaxf((float)x, 1.0f));
    curs[t] = beg + rs;
    __syncthreads();
    for (int i = beg + t; i < end; i += 256) {
        unsigned int e = ebufD[i];
        int pos = atomicAdd(&curs[e >> 17], 1);
        csr_src[pos] = (int)(e & 0x1FFFFu);
    }
}

// ---------------- bdeg: per-bucket src counts -> norm_src ----------------
__global__ __launch_bounds__(256) void k_bdeg(const int* __restrict__ bucketStart,
                                              const unsigned char* __restrict__ ebufS,
                                              float* __restrict__ norm_src) {
    __shared__ int cnt[256];
    const int t = threadIdx.x, b = blockIdx.x;
    const int beg = bucketStart[NB_D + b] - N_EDGES;
    const int end = bucketStart[NB_D + b + 1] - N_EDGES;
    cnt[t] = 0;
    __syncthreads();
    for (int i = beg + t; i < end; i += 256)
        atomicAdd(&cnt[ebufS[i]], 1);
    __syncthreads();
    int node = b * 256 + t;
    if (node < N_NODES)
        norm_src[node] = 1.0f / sqrtf(fmaxf((float)cnt[t], 1.0f));
}

// ---------------- GEMM1: h1[i][j] = ns[i] * sum_k x[i][k] W1[k][j] ----------------
__global__ __launch_bounds__(256) void k_gemm1(
        const float* __restrict__ x, const float* __restrict__ W1,
        const float* __restrict__ norm_src, float* __restrict__ h1) {
    __shared__ float Ws[IN_F * HID];        // 32 KB
    __shared__ float xs[16 * 132];          // stride 132 -> 2-way banks (free)
    const int t = threadIdx.x;
    for (int i = t * 4; i < IN_F * HID; i += 256 * 4)
        *(float4*)&Ws[i] = *(const float4*)&W1[i];
    const int jq = t & 15;
    const int rl = t >> 4;
    for (int row0 = blockIdx.x * 16; row0 < N_NODES; row0 += gridDim.x * 16) {
        __syncthreads();
        for (int i = t; i < 16 * (IN_F / 4); i += 256) {
            int rr = i >> 5, cc = i & 31;
            int gr = row0 + rr;
            float4 v = (gr < N_NODES) ? *(const float4*)&x[(size_t)gr * IN_F + cc * 4]
                                      : float4{0.f, 0.f, 0.f, 0.f};
            *(float4*)&xs[rr * 132 + cc * 4] = v;
        }
        __syncthreads();
        int r = row0 + rl;
        if (r < N_NODES) {
            float4 acc = {0.f, 0.f, 0.f, 0.f};
            #pragma unroll
            for (int k = 0; k < IN_F; k += 4) {
                float4 xv = *(float4*)&xs[rl * 132 + k];
                float4 w0 = *(float4*)&Ws[(k + 0) * HID + jq * 4];
                float4 w1 = *(float4*)&Ws[(k + 1) * HID + jq * 4];
                float4 w2 = *(float4*)&Ws[(k + 2) * HID + jq * 4];
                float4 w3 = *(float4*)&Ws[(k + 3) * HID + jq * 4];
                acc.x += xv.x * w0.x + xv.y * w1.x + xv.z * w2.x + xv.w * w3.x;
                acc.y += xv.x * w0.y + xv.y * w1.y + xv.z * w2.y + xv.w * w3.y;
                acc.z += xv.x * w0.z + xv.y * w1.z + xv.z * w2.z + xv.w * w3.z;
                acc.w += xv.x * w0.w + xv.y * w1.w + xv.z * w2.w + xv.w * w3.w;
            }
            float ns = norm_src[r];
            acc.x *= ns; acc.y *= ns; acc.z *= ns; acc.w *= ns;
            *(float4*)&h1[(size_t)r * HID + jq * 4] = acc;
        }
    }
}

// ---------------- agg1: one wave per node, 64 lanes = 64 feats ----------------
__global__ __launch_bounds__(256) void k_agg1(
        const int* __restrict__ row_start, const int* __restrict__ csr_src,
        const float* __restrict__ h1, const float* __restrict__ nd,
        const float* __restrict__ b1, float* __restrict__ h1r) {
    int node = blockIdx.x * 4 + (threadIdx.x >> 6);
    int lane = threadIdx.x & 63;
    if (node >= N_NODES) return;
    int beg = row_start[node];
    int end = row_start[node + 1];
    float acc = 0.f;
    int p = beg;
    for (; p + 1 < end; p += 2) {
        int s0 = csr_src[p], s1 = csr_src[p + 1];
        float a = h1[(size_t)s0 * HID + lane];
        float b = h1[(size_t)s1 * HID + lane];
        acc += a; acc += b;
    }
    if (p < end) acc += h1[(size_t)csr_src[p] * HID + lane];
    float v = acc * nd[node] + b1[lane];
    h1r[(size_t)node * HID + lane] = fmaxf(v, 0.f);
}

// ---------------- GEMM2 ----------------
__global__ __launch_bounds__(256) void k_gemm2(
        const float* __restrict__ hin, const float* __restrict__ W2,
        const float* __restrict__ norm_src, float* __restrict__ h2) {
    __shared__ float Ws[HID * NC];          // 4 KB
    __shared__ float xs[64 * 68];           // stride 68 -> 2-way banks (free)
    const int t = threadIdx.x;
    for (int i = t * 4; i < HID * NC; i += 256 * 4)
        *(float4*)&Ws[i] = *(const float4*)&W2[i];
    const int jq = t & 3;
    const int rl = t >> 2;
    for (int row0 = blockIdx.x * 64; row0 < N_NODES; row0 += gridDim.x * 64) {
        __syncthreads();
        for (int i = t; i < 64 * (HID / 4); i += 256) {
            int rr = i >> 4, cc = i & 15;
            int gr = row0 + rr;
            float4 v = (gr < N_NODES) ? *(const float4*)&hin[(size_t)gr * HID + cc * 4]
                                      : float4{0.f, 0.f, 0.f, 0.f};
            *(float4*)&xs[rr * 68 + cc * 4] = v;
        }
        __syncthreads();
        int r = row0 + rl;
        if (r < N_NODES) {
            float4 acc = {0.f, 0.f, 0.f, 0.f};
            #pragma unroll
            for (int k = 0; k < HID; k += 4) {
                float4 xv = *(float4*)&xs[rl * 68 + k];
                float4 w0 = *(float4*)&Ws[(k + 0) * NC + jq * 4];
                float4 w1 = *(float4*)&Ws[(k + 1) * NC + jq * 4];
                float4 w2 = *(float4*)&Ws[(k + 2) * NC + jq * 4];
                float4 w3 = *(float4*)&Ws[(k + 3) * NC + jq * 4];
                acc.x += xv.x * w0.x + xv.y * w1.x + xv.z * w2.x + xv.w * w3.x;
                acc.y += xv.x * w0.y + xv.y * w1.y + xv.z * w2.y + xv.w * w3.y;
                acc.z += xv.x * w0.z + xv.y * w1.z + xv.z * w2.z + xv.w * w3.z;
                acc.w += xv.x * w0.w + xv.y * w1.w + xv.z * w2.w + xv.w * w3.w;
            }
            float ns = norm_src[r];
            acc.x *= ns; acc.y *= ns; acc.z *= ns; acc.w *= ns;
            *(float4*)&h2[(size_t)r * NC + jq * 4] = acc;
        }
    }
}

// ---------------- agg2 + softmax: 16 lanes per node ----------------
__global__ __launch_bounds__(256) void k_agg2(
        const int* __restrict__ row_start, const int* __restrict__ csr_src,
        const float* __restrict__ h2, const float* __restrict__ nd,
        const float* __restrict__ b2, float* __restrict__ out) {
    int t = threadIdx.x;
    int node = blockIdx.x * 16 + (t >> 4);
    int lane = t & 15;
    if (node >= N_NODES) return;
    int beg = row_start[node];
    int end = row_start[node + 1];
    float acc = 0.f;
    int p = beg;
    for (; p + 1 < end; p += 2) {
        int s0 = csr_src[p], s1 = csr_src[p + 1];
        float a = h2[(size_t)s0 * NC + lane];
        float b = h2[(size_t)s1 * NC + lane];
        acc += a; acc += b;
    }
    if (p < end) acc += h2[(size_t)csr_src[p] * NC + lane];
    float val = acc * nd[node] + b2[lane];
    float m = val;
    #pragma unroll
    for (int d = 8; d >= 1; d >>= 1) m = fmaxf(m, __shfl_xor(m, d, 16));
    float e = __expf(val - m);
    float s = e;
    #pragma unroll
    for (int d = 8; d >= 1; d >>= 1) s += __shfl_xor(s, d, 16);
    out[(size_t)node * NC + lane] = e / s;
}

extern "C" void kernel_launch(void* const* d_in, const int* in_sizes, int n_in,
                              void* d_out, int out_size, void* d_ws, size_t ws_size,
                              hipStream_t stream) {
    const float* x   = (const float*)d_in[0];
    const int*   src = (const int*)  d_in[1];
    const int*   dst = (const int*)  d_in[2];
    const float* W1  = (const float*)d_in[3];
    const float* b1  = (const float*)d_in[4];
    const float* W2  = (const float*)d_in[5];
    const float* b2  = (const float*)d_in[6];
    float* out = (float*)d_out;

    // ws layout (4-byte words), N=100000, E=1.6M:
    //   [0,N)       norm_src
    //   [N,2N)      norm_dst
    //   [2N,66N)    h1 (gemm1 out); h2 (16N) aliases after agg1
    //   [66N,130N)  h1r (agg1 out); ebufD (E words) + ebufS (E bytes) alias
    //               this region BEFORE agg1 runs (consumed by bcsr/bdeg).
    //   [130N,131N] row_start (N+1)
    //   [131N+8, +782+1)           bucketStart
    //   [131N+800, +128*782)       gHist / gCursor (in-place)
    //   [131N+800+100096, +E)      csr_src
    // total ~= 131N + 100896 + E words ~= 59.2 MB
    const size_t N = N_NODES;
    float* ws       = (float*)d_ws;
    int*   wsI      = (int*)d_ws;
    float* norm_src = ws;
    float* norm_dst = ws + N;
    float* h1       = ws + 2 * N;
    float* h2       = ws + 2 * N;            // alias (h1 dead after agg1)
    float* h1r      = ws + 66 * N;
    unsigned int*  ebufD = (unsigned int*)(wsI + 66 * N);          // E words
    unsigned char* ebufS = (unsigned char*)(wsI + 66 * N + N_EDGES); // E bytes
    int*   row_st   = wsI + 130 * N;
    int*   bstart   = wsI + 131 * N + 8;
    int*   gHist    = wsI + 131 * N + 800;
    int*   csr_src  = wsI + 131 * N + 800 + NBLK_P * NB_ALL;

    k_p1  <<<NBLK_P, 256, 0, stream>>>(src, dst, gHist);
    k_p2  <<<1, 1024, 0, stream>>>(gHist, bstart);
    k_p3  <<<NBLK_P, 256, 0, stream>>>(src, dst, gHist, ebufD, ebufS);
    k_bcsr<<<NB_D, 256, 0, stream>>>(bstart, ebufD, row_st, norm_dst, csr_src);
    k_bdeg<<<NB_D, 256, 0, stream>>>(bstart, ebufS, norm_src);
    k_gemm1<<<2048, 256, 0, stream>>>(x, W1, norm_src, h1);
    k_agg1<<<(N_NODES + 3) / 4, 256, 0, stream>>>(row_st, csr_src, h1,
                                                  norm_dst, b1, h1r);
    k_gemm2<<<2048, 256, 0, stream>>>(h1r, W2, norm_src, h2);
    k_agg2<<<(N_NODES + 15) / 16, 256, 0, stream>>>(row_st, csr_src, h2,
                                                    norm_dst, b2, out);
}

// Round 4
// 323.366 us; speedup vs baseline: 2.3363x; 1.1643x over previous
//
#include <hip/hip_runtime.h>
#include <math.h>

// GCN 2-layer, fp32. Round 4: MLP-deep float4 gathers in agg1/agg2
// (latency-bound fix), 4x4 register-tiled gemm1. Build unchanged from R3.

constexpr int N_NODES = 100000;
constexpr int N_EDGES = 1600000;
constexpr int IN_F    = 128;
constexpr int HID     = 64;
constexpr int NC      = 16;

constexpr int NBLK_P  = 128;                 // partition blocks
constexpr int EPB     = N_EDGES / NBLK_P;    // 12500 edges per partition block
constexpr int NB_D    = 391;                 // dst buckets (256 nodes each)
constexpr int NB_ALL  = 2 * NB_D;            // 782: [0,391) dst, [391,782) src

// ---------------- p1: per-block bucket histogram (both keys) ----------------
__global__ __launch_bounds__(256) void k_p1(const int* __restrict__ src,
                                            const int* __restrict__ dst,
                                            int* __restrict__ gHist) {
    __shared__ int hist[NB_ALL];
    const int t = threadIdx.x, b = blockIdx.x;
    for (int i = t; i < NB_ALL; i += 256) hist[i] = 0;
    __syncthreads();
    const int beg = b * EPB, end = beg + EPB;
    for (int i = beg + t; i < end; i += 256) {
        atomicAdd(&hist[dst[i] >> 8], 1);
        atomicAdd(&hist[NB_D + (src[i] >> 8)], 1);
    }
    __syncthreads();
    for (int i = t; i < NB_ALL; i += 256)
        gHist[b * NB_ALL + i] = hist[i];     // coalesced
}

// ---------------- p2: column scan -> cursors (in place) + bucket starts ------
__global__ __launch_bounds__(1024) void k_p2(int* __restrict__ gHist,
                                             int* __restrict__ bucketStart) {
    const int t = threadIdx.x;               // 1024 threads, 782 active columns
    int total = 0;
    if (t < NB_ALL) {
        for (int blk = 0; blk < NBLK_P; ++blk) {
            int idx = blk * NB_ALL + t;      // coalesced across threads
            int v = gHist[idx];
            gHist[idx] = total;              // local exclusive prefix
            total += v;
        }
    }
    int v = total;
    int lane = t & 63, wid = t >> 6;
    #pragma unroll
    for (int d = 1; d < 64; d <<= 1) { int u = __shfl_up(v, d, 64); if (lane >= d) v += u; }
    __shared__ int wsum[16];
    if (lane == 63) wsum[wid] = v;
    __syncthreads();
    int woff = 0;
    for (int w = 0; w < wid; ++w) woff += wsum[w];
    int colStart = woff + v - total;         // exclusive
    if (t < NB_ALL) {
        bucketStart[t] = colStart;
        if (t == NB_ALL - 1) bucketStart[NB_ALL] = colStart + total;  // = 2E
        for (int blk = 0; blk < NBLK_P; ++blk)
            gHist[blk * NB_ALL + t] += colStart;   // now global cursors
    }
}

// ---------------- p3: scatter edges into buckets (LDS cursors) ----------------
__global__ __launch_bounds__(256) void k_p3(const int* __restrict__ src,
                                            const int* __restrict__ dst,
                                            const int* __restrict__ gCursor,
                                            unsigned int* __restrict__ ebufD,
                                            unsigned char* __restrict__ ebufS) {
    __shared__ int curs[NB_ALL];
    const int t = threadIdx.x, b = blockIdx.x;
    for (int i = t; i < NB_ALL; i += 256) curs[i] = gCursor[b * NB_ALL + i];
    __syncthreads();
    const int beg = b * EPB, end = beg + EPB;
    for (int i = beg + t; i < end; i += 256) {
        int d = dst[i], s = src[i];
        int pD = atomicAdd(&curs[d >> 8], 1);
        ebufD[pD] = ((unsigned)(d & 255) << 17) | (unsigned)s;
        int pS = atomicAdd(&curs[NB_D + (s >> 8)], 1);
        ebufS[pS - N_EDGES] = (unsigned char)(s & 255);
    }
}

// ---------------- bcsr: per-bucket CSR build + norm_dst + row_start ----------
__global__ __launch_bounds__(256) void k_bcsr(const int* __restrict__ bucketStart,
                                              const unsigned int* __restrict__ ebufD,
                                              int* __restrict__ row_start,
                                              float* __restrict__ norm_dst,
                                              int* __restrict__ csr_src) {
    __shared__ int cnt[256];
    __shared__ int curs[256];
    __shared__ int wsum[4];
    const int t = threadIdx.x, b = blockIdx.x;
    const int beg = bucketStart[b], end = bucketStart[b + 1];
    cnt[t] = 0;
    __syncthreads();
    for (int i = beg + t; i < end; i += 256)
        atomicAdd(&cnt[ebufD[i] >> 17], 1);
    __syncthreads();
    int x = cnt[t];
    int v = x;
    int lane = t & 63, wid = t >> 6;
    #pragma unroll
    for (int d = 1; d < 64; d <<= 1) { int u = __shfl_up(v, d, 64); if (lane >= d) v += u; }
    if (lane == 63) wsum[wid] = v;
    __syncthreads();
    int woff = 0;
    for (int w = 0; w < wid; ++w) woff += wsum[w];
    int rs = woff + v - x;                   // exclusive prefix
    int node = b * 256 + t;
    if (node <= N_NODES) row_start[node] = beg + rs;
    if (node <  N_NODES) norm_dst[node] = 1.0f / sqrtf(fmaxf((float)x, 1.0f));
    curs[t] = beg + rs;
    __syncthreads();
    for (int i = beg + t; i < end; i += 256) {
        unsigned int e = ebufD[i];
        int pos = atomicAdd(&curs[e >> 17], 1);
        csr_src[pos] = (int)(e & 0x1FFFFu);
    }
}

// ---------------- bdeg: per-bucket src counts -> norm_src ----------------
__global__ __launch_bounds__(256) void k_bdeg(const int* __restrict__ bucketStart,
                                              const unsigned char* __restrict__ ebufS,
                                              float* __restrict__ norm_src) {
    __shared__ int cnt[256];
    const int t = threadIdx.x, b = blockIdx.x;
    const int beg = bucketStart[NB_D + b] - N_EDGES;
    const int end = bucketStart[NB_D + b + 1] - N_EDGES;
    cnt[t] = 0;
    __syncthreads();
    for (int i = beg + t; i < end; i += 256)
        atomicAdd(&cnt[ebufS[i]], 1);
    __syncthreads();
    int node = b * 256 + t;
    if (node < N_NODES)
        norm_src[node] = 1.0f / sqrtf(fmaxf((float)cnt[t], 1.0f));
}

// ---------------- GEMM1: 64-row tiles, 4x4 register blocking ----------------
#define GEMM_STEP(accr, xvr) \
    accr.x += xvr.x*w0.x + xvr.y*w1.x + xvr.z*w2.x + xvr.w*w3.x; \
    accr.y += xvr.x*w0.y + xvr.y*w1.y + xvr.z*w2.y + xvr.w*w3.y; \
    accr.z += xvr.x*w0.z + xvr.y*w1.z + xvr.z*w2.z + xvr.w*w3.z; \
    accr.w += xvr.x*w0.w + xvr.y*w1.w + xvr.z*w2.w + xvr.w*w3.w;

__global__ __launch_bounds__(256) void k_gemm1(
        const float* __restrict__ x, const float* __restrict__ W1,
        const float* __restrict__ norm_src, float* __restrict__ h1) {
    __shared__ float Ws[IN_F * HID];     // 32 KB
    __shared__ float xs[64 * 68];        // 17.4 KB: 64 rows x 64 k-cols, pad->2-way (free)
    const int t = threadIdx.x;
    for (int i = t * 4; i < IN_F * HID; i += 1024)
        *(float4*)&Ws[i] = *(const float4*)&W1[i];
    const int cg = t & 15;               // cols cg*4..+3
    const int rg = t >> 4;               // rows rg*4..+3
    const int row0 = blockIdx.x * 64;
    float4 acc0 = {0,0,0,0}, acc1 = {0,0,0,0}, acc2 = {0,0,0,0}, acc3 = {0,0,0,0};
    for (int kh = 0; kh < 2; ++kh) {
        __syncthreads();                 // orders Ws load (kh=0) / xs reuse (kh=1)
        for (int i = t; i < 64 * 16; i += 256) {
            int rr = i >> 4, cc = i & 15;
            int gr = row0 + rr;
            float4 v = (gr < N_NODES) ? *(const float4*)&x[(size_t)gr * IN_F + kh * 64 + cc * 4]
                                      : float4{0.f, 0.f, 0.f, 0.f};
            *(float4*)&xs[rr * 68 + cc * 4] = v;
        }
        __syncthreads();
        #pragma unroll
        for (int k = 0; k < 64; k += 4) {
            float4 xv0 = *(float4*)&xs[(rg * 4 + 0) * 68 + k];
            float4 xv1 = *(float4*)&xs[(rg * 4 + 1) * 68 + k];
            float4 xv2 = *(float4*)&xs[(rg * 4 + 2) * 68 + k];
            float4 xv3 = *(float4*)&xs[(rg * 4 + 3) * 68 + k];
            const int kg = kh * 64 + k;
            float4 w0 = *(float4*)&Ws[(kg + 0) * HID + cg * 4];
            float4 w1 = *(float4*)&Ws[(kg + 1) * HID + cg * 4];
            float4 w2 = *(float4*)&Ws[(kg + 2) * HID + cg * 4];
            float4 w3 = *(float4*)&Ws[(kg + 3) * HID + cg * 4];
            GEMM_STEP(acc0, xv0)
            GEMM_STEP(acc1, xv1)
            GEMM_STEP(acc2, xv2)
            GEMM_STEP(acc3, xv3)
        }
    }
    const int r0 = row0 + rg * 4;
    #pragma unroll
    for (int r = 0; r < 4; ++r) {
        int rr = r0 + r;
        if (rr < N_NODES) {
            float4 a = (r == 0) ? acc0 : (r == 1) ? acc1 : (r == 2) ? acc2 : acc3;
            float ns = norm_src[rr];
            a.x *= ns; a.y *= ns; a.z *= ns; a.w *= ns;
            *(float4*)&h1[(size_t)rr * HID + cg * 4] = a;
        }
    }
}

// ---------------- agg1: 16 lanes/node, float4 gathers, 4-edge unroll ---------
__global__ __launch_bounds__(256) void k_agg1(
        const int* __restrict__ row_start, const int* __restrict__ csr_src,
        const float* __restrict__ h1, const float* __restrict__ nd,
        const float* __restrict__ b1, float* __restrict__ h1r) {
    int node = blockIdx.x * 16 + (threadIdx.x >> 4);
    int q = threadIdx.x & 15;            // feat quad
    if (node >= N_NODES) return;
    int beg = row_start[node], end = row_start[node + 1];
    float4 acc = {0.f, 0.f, 0.f, 0.f};
    int p = beg;
    for (; p + 4 <= end; p += 4) {
        int s0 = csr_src[p + 0], s1 = csr_src[p + 1];
        int s2 = csr_src[p + 2], s3 = csr_src[p + 3];
        float4 a0 = *(const float4*)&h1[(size_t)s0 * HID + q * 4];
        float4 a1 = *(const float4*)&h1[(size_t)s1 * HID + q * 4];
        float4 a2 = *(const float4*)&h1[(size_t)s2 * HID + q * 4];
        float4 a3 = *(const float4*)&h1[(size_t)s3 * HID + q * 4];
        acc.x += a0.x + a1.x + a2.x + a3.x;
        acc.y += a0.y + a1.y + a2.y + a3.y;
        acc.z += a0.z + a1.z + a2.z + a3.z;
        acc.w += a0.w + a1.w + a2.w + a3.w;
    }
    for (; p < end; ++p) {
        int s = csr_src[p];
        float4 a = *(const float4*)&h1[(size_t)s * HID + q * 4];
        acc.x += a.x; acc.y += a.y; acc.z += a.z; acc.w += a.w;
    }
    float n = nd[node];
    float4 bb = *(const float4*)&b1[q * 4];
    float4 o;
    o.x = fmaxf(acc.x * n + bb.x, 0.f);
    o.y = fmaxf(acc.y * n + bb.y, 0.f);
    o.z = fmaxf(acc.z * n + bb.z, 0.f);
    o.w = fmaxf(acc.w * n + bb.w, 0.f);
    *(float4*)&h1r[(size_t)node * HID + q * 4] = o;
}

// ---------------- GEMM2: 64-row tiles (round-3 structure) ----------------
__global__ __launch_bounds__(256) void k_gemm2(
        const float* __restrict__ hin, const float* __restrict__ W2,
        const float* __restrict__ norm_src, float* __restrict__ h2) {
    __shared__ float Ws[HID * NC];          // 4 KB
    __shared__ float xs[64 * 68];           // stride 68 -> 2-way banks (free)
    const int t = threadIdx.x;
    for (int i = t * 4; i < HID * NC; i += 256 * 4)
        *(float4*)&Ws[i] = *(const float4*)&W2[i];
    const int jq = t & 3;
    const int rl = t >> 2;
    const int row0 = blockIdx.x * 64;
    __syncthreads();
    for (int i = t; i < 64 * (HID / 4); i += 256) {
        int rr = i >> 4, cc = i & 15;
        int gr = row0 + rr;
        float4 v = (gr < N_NODES) ? *(const float4*)&hin[(size_t)gr * HID + cc * 4]
                                  : float4{0.f, 0.f, 0.f, 0.f};
        *(float4*)&xs[rr * 68 + cc * 4] = v;
    }
    __syncthreads();
    int r = row0 + rl;
    if (r < N_NODES) {
        float4 acc = {0.f, 0.f, 0.f, 0.f};
        #pragma unroll
        for (int k = 0; k < HID; k += 4) {
            float4 xv = *(float4*)&xs[rl * 68 + k];
            float4 w0 = *(float4*)&Ws[(k + 0) * NC + jq * 4];
            float4 w1 = *(float4*)&Ws[(k + 1) * NC + jq * 4];
            float4 w2 = *(float4*)&Ws[(k + 2) * NC + jq * 4];
            float4 w3 = *(float4*)&Ws[(k + 3) * NC + jq * 4];
            GEMM_STEP(acc, xv)
        }
        float ns = norm_src[r];
        acc.x *= ns; acc.y *= ns; acc.z *= ns; acc.w *= ns;
        *(float4*)&h2[(size_t)r * NC + jq * 4] = acc;
    }
}

// ---------------- agg2 + softmax: 4 lanes/node, float4, 4-edge unroll --------
__global__ __launch_bounds__(256) void k_agg2(
        const int* __restrict__ row_start, const int* __restrict__ csr_src,
        const float* __restrict__ h2, const float* __restrict__ nd,
        const float* __restrict__ b2, float* __restrict__ out) {
    int t = threadIdx.x;
    int node = blockIdx.x * 64 + (t >> 2);
    int sub = t & 3;                     // feats sub*4..+3
    if (node >= N_NODES) return;
    int beg = row_start[node], end = row_start[node + 1];
    float4 acc = {0.f, 0.f, 0.f, 0.f};
    int p = beg;
    for (; p + 4 <= end; p += 4) {
        int s0 = csr_src[p + 0], s1 = csr_src[p + 1];
        int s2 = csr_src[p + 2], s3 = csr_src[p + 3];
        float4 a0 = *(const float4*)&h2[(size_t)s0 * NC + sub * 4];
        float4 a1 = *(const float4*)&h2[(size_t)s1 * NC + sub * 4];
        float4 a2 = *(const float4*)&h2[(size_t)s2 * NC + sub * 4];
        float4 a3 = *(const float4*)&h2[(size_t)s3 * NC + sub * 4];
        acc.x += a0.x + a1.x + a2.x + a3.x;
        acc.y += a0.y + a1.y + a2.y + a3.y;
        acc.z += a0.z + a1.z + a2.z + a3.z;
        acc.w += a0.w + a1.w + a2.w + a3.w;
    }
    for (; p < end; ++p) {
        int s = csr_src[p];
        float4 a = *(const float4*)&h2[(size_t)s * NC + sub * 4];
        acc.x += a.x; acc.y += a.y; acc.z += a.z; acc.w += a.w;
    }
    float n = nd[node];
    float4 bb = *(const float4*)&b2[sub * 4];
    float4 vv;
    vv.x = acc.x * n + bb.x;
    vv.y = acc.y * n + bb.y;
    vv.z = acc.z * n + bb.z;
    vv.w = acc.w * n + bb.w;
    float m = fmaxf(fmaxf(vv.x, vv.y), fmaxf(vv.z, vv.w));
    m = fmaxf(m, __shfl_xor(m, 1, 4));
    m = fmaxf(m, __shfl_xor(m, 2, 4));
    float e0 = __expf(vv.x - m), e1 = __expf(vv.y - m);
    float e2 = __expf(vv.z - m), e3 = __expf(vv.w - m);
    float s = e0 + e1 + e2 + e3;
    s += __shfl_xor(s, 1, 4);
    s += __shfl_xor(s, 2, 4);
    float inv = 1.0f / s;
    float4 o = { e0 * inv, e1 * inv, e2 * inv, e3 * inv };
    *(float4*)&out[(size_t)node * NC + sub * 4] = o;
}

extern "C" void kernel_launch(void* const* d_in, const int* in_sizes, int n_in,
                              void* d_out, int out_size, void* d_ws, size_t ws_size,
                              hipStream_t stream) {
    const float* x   = (const float*)d_in[0];
    const int*   src = (const int*)  d_in[1];
    const int*   dst = (const int*)  d_in[2];
    const float* W1  = (const float*)d_in[3];
    const float* b1  = (const float*)d_in[4];
    const float* W2  = (const float*)d_in[5];
    const float* b2  = (const float*)d_in[6];
    float* out = (float*)d_out;

    // ws layout (4-byte words), N=100000, E=1.6M:
    //   [0,N) norm_src | [N,2N) norm_dst
    //   [2N,66N)   h1; h2 (16N) aliases after agg1
    //   [66N,130N) h1r; ebufD (E words)+ebufS (E bytes) alias before agg1
    //   [130N,131N] row_start (N+1)
    //   [131N+8 ..)  bucketStart | gHist | csr_src
    const size_t N = N_NODES;
    float* ws       = (float*)d_ws;
    int*   wsI      = (int*)d_ws;
    float* norm_src = ws;
    float* norm_dst = ws + N;
    float* h1       = ws + 2 * N;
    float* h2       = ws + 2 * N;            // alias (h1 dead after agg1)
    float* h1r      = ws + 66 * N;
    unsigned int*  ebufD = (unsigned int*)(wsI + 66 * N);            // E words
    unsigned char* ebufS = (unsigned char*)(wsI + 66 * N + N_EDGES); // E bytes
    int*   row_st   = wsI + 130 * N;
    int*   bstart   = wsI + 131 * N + 8;
    int*   gHist    = wsI + 131 * N + 800;
    int*   csr_src  = wsI + 131 * N + 800 + NBLK_P * NB_ALL;

    k_p1  <<<NBLK_P, 256, 0, stream>>>(src, dst, gHist);
    k_p2  <<<1, 1024, 0, stream>>>(gHist, bstart);
    k_p3  <<<NBLK_P, 256, 0, stream>>>(src, dst, gHist, ebufD, ebufS);
    k_bcsr<<<NB_D, 256, 0, stream>>>(bstart, ebufD, row_st, norm_dst, csr_src);
    k_bdeg<<<NB_D, 256, 0, stream>>>(bstart, ebufS, norm_src);
    k_gemm1<<<(N_NODES + 63) / 64, 256, 0, stream>>>(x, W1, norm_src, h1);
    k_agg1<<<(N_NODES + 15) / 16, 256, 0, stream>>>(row_st, csr_src, h1,
                                                    norm_dst, b1, h1r);
    k_gemm2<<<(N_NODES + 63) / 64, 256, 0, stream>>>(h1r, W2, norm_src, h2);
    k_agg2<<<(N_NODES + 63) / 64, 256, 0, stream>>>(row_st, csr_src, h2,
                                                    norm_dst, b2, out);
}